// Round 8
// baseline (373.972 us; speedup 1.0000x reference)
//
#include <hip/hip_runtime.h>

// pyGAMNet round 7 kernel (re-submit; R7 bench was a broker timeout).
// Scalar-path weights (s_load) + 4 rows/lane amortization.
// R6 lesson: per-FMA weight reads bound the LDS pipe; R4 lesson: 1:1
// s_load:FMA is latency-bound. 1:4 ratio + block-shared weight stream fixes both.

constexpr int NCOLS = 64;
constexpr int NNUM  = 48;
constexpr int NCLS  = 32;
constexpr int H0N   = 40;
constexpr int H1N   = 20;

#define BLOCK 256
#define FPB   6     // numeric features per block (8 feature-groups cover 48)
#define NRG   128   // row-groups (131072 / 1024 rows-per-block)
#define RPW   256   // rows per wave (4 per lane, q-interleaved by 64)

__global__ __launch_bounds__(BLOCK, 4)
void gam_kernel(const float* __restrict__ inp,
                const float* __restrict__ W0, const float* __restrict__ b0,
                const float* __restrict__ W1, const float* __restrict__ b1,
                const float* __restrict__ W2, const float* __restrict__ b2,
                const float* __restrict__ cbias,
                float* __restrict__ out)
{
    __shared__ float cb[2 * NCLS];   // this block's 2 categorical tables

    const int t    = threadIdx.x;
    const int lane = t & 63;
    const int wv   = t >> 6;
    const int fg   = blockIdx.x >> 7;          // 0..7, block-uniform
    const int rg   = blockIdx.x & (NRG - 1);   // 0..127 fastest -> same XCD per rg
    const int rowbase = rg * (4 * RPW) + wv * RPW + lane;   // + q*64

    if (t < 2 * NCLS) cb[t] = cbias[2 * fg * NCLS + t];
    __syncthreads();

    const float* __restrict__ rp = inp + (long long)rowbase * NCOLS;

    // categorical indices (consumed at the end; latency hidden under compute)
    int cidx0[4], cidx1[4];
    #pragma unroll
    for (int q = 0; q < 4; ++q) {
        cidx0[q] = (int)rp[q * 64 * NCOLS + NNUM + 2 * fg + 0];
        cidx1[q] = (int)rp[q * 64 * NCOLS + NNUM + 2 * fg + 1];
    }

    // rotating x prefetch (named regs, no runtime-indexed arrays)
    float xc0 = rp[0 * 64 * NCOLS + fg * FPB];
    float xc1 = rp[1 * 64 * NCOLS + fg * FPB];
    float xc2 = rp[2 * 64 * NCOLS + fg * FPB];
    float xc3 = rp[3 * 64 * NCOLS + fg * FPB];

    #pragma unroll 1
    for (int j = 0; j < FPB; ++j) {
        const int f = fg * FPB + j;                       // block-uniform -> s_load
        const float* __restrict__ w0f = W0 + f * H0N;
        const float* __restrict__ b0f = b0 + f * H0N;
        const float* __restrict__ w1f = W1 + f * H0N * H1N;
        const float* __restrict__ b1f = b1 + f * H1N;
        const float* __restrict__ w2f = W2 + f * H1N;

        float xn0 = 0.f, xn1 = 0.f, xn2 = 0.f, xn3 = 0.f;
        if (j < FPB - 1) {                                // prefetch next feature's x
            xn0 = rp[0 * 64 * NCOLS + f + 1];
            xn1 = rp[1 * 64 * NCOLS + f + 1];
            xn2 = rp[2 * 64 * NCOLS + f + 1];
            xn3 = rp[3 * 64 * NCOLS + f + 1];
        }

        float h10[H1N], h11[H1N], h12[H1N], h13[H1N];     // 80 VGPR accumulators
        #pragma unroll
        for (int o = 0; o < H1N; ++o) {
            const float bv = b1f[o];
            h10[o] = bv; h11[o] = bv; h12[o] = bv; h13[o] = bv;
        }

        #pragma unroll 10
        for (int k = 0; k < H0N; ++k) {
            const float w0k = w0f[k], b0k = b0f[k];       // SGPR
            const float a0 = fmaxf(fmaf(xc0, w0k, b0k), 0.f);
            const float a1 = fmaxf(fmaf(xc1, w0k, b0k), 0.f);
            const float a2 = fmaxf(fmaf(xc2, w0k, b0k), 0.f);
            const float a3 = fmaxf(fmaf(xc3, w0k, b0k), 0.f);
            const float* __restrict__ wk = w1f + k * H1N;
            #pragma unroll
            for (int o = 0; o < H1N; ++o) {
                const float w = wk[o];                    // SGPR, reused 4x
                h10[o] = fmaf(a0, w, h10[o]);
                h11[o] = fmaf(a1, w, h11[o]);
                h12[o] = fmaf(a2, w, h12[o]);
                h13[o] = fmaf(a3, w, h13[o]);
            }
        }

        const float b2v = b2[f];
        float acc0 = b2v, acc1 = b2v, acc2 = b2v, acc3 = b2v;
        #pragma unroll
        for (int o = 0; o < H1N; ++o) {
            const float w = w2f[o];
            acc0 = fmaf(fmaxf(h10[o], 0.f), w, acc0);
            acc1 = fmaf(fmaxf(h11[o], 0.f), w, acc1);
            acc2 = fmaf(fmaxf(h12[o], 0.f), w, acc2);
            acc3 = fmaf(fmaxf(h13[o], 0.f), w, acc3);
        }

        float* op = out + (long long)rowbase * NCOLS + f;
        op[0 * 64 * NCOLS] = acc0;
        op[1 * 64 * NCOLS] = acc1;
        op[2 * 64 * NCOLS] = acc2;
        op[3 * 64 * NCOLS] = acc3;

        xc0 = xn0; xc1 = xn1; xc2 = xn2; xc3 = xn3;
    }

    // categorical outputs (cols 48+2fg, 49+2fg)
    {
        float* op = out + (long long)rowbase * NCOLS + NNUM + 2 * fg;
        #pragma unroll
        for (int q = 0; q < 4; ++q) {
            op[q * 64 * NCOLS + 0] = cb[cidx0[q]];
            op[q * 64 * NCOLS + 1] = cb[NCLS + cidx1[q]];
        }
    }
}

extern "C" void kernel_launch(void* const* d_in, const int* in_sizes, int n_in,
                              void* d_out, int out_size, void* d_ws, size_t ws_size,
                              hipStream_t stream) {
    const float* inp   = (const float*)d_in[0];
    const float* W0    = (const float*)d_in[1];
    const float* b0    = (const float*)d_in[2];
    const float* W1    = (const float*)d_in[3];
    const float* b1    = (const float*)d_in[4];
    const float* W2    = (const float*)d_in[5];
    const float* b2    = (const float*)d_in[6];
    const float* cbias = (const float*)d_in[7];
    float* out = (float*)d_out;

    dim3 grid(8 * NRG);   // fg-major, rg fastest: 1024 blocks
    dim3 block(BLOCK);
    gam_kernel<<<grid, block, 0, stream>>>(inp, W0, b0, W1, b1, W2, b2, cbias, out);
}

// Round 9
// 308.974 us; speedup vs baseline: 1.2104x; 1.2104x over previous
//
#include <hip/hip_runtime.h>

// pyGAMNet round 9: R4's DRAM-clean 16-col (64B) windows + R7's 4-rows/lane
// weight amortization. Block = 4 waves x 256 rows x 16 cols; wave = 4 features.
// R8 lesson: column-slicing below 64B granularity costs 9x fetch amplification.

constexpr int NCOLS = 64;
constexpr int NNUM  = 48;
constexpr int NCLS  = 32;
constexpr int H0N   = 40;
constexpr int H1N   = 20;

#define BLOCK 256
#define RPB   256    // rows per block (4 per lane: row = row0 + q*64 + lane)
#define NRG   512    // row-groups = 131072 / 256

__global__ __launch_bounds__(BLOCK, 4)
void gam_kernel(const float* __restrict__ inp,
                const float* __restrict__ W0, const float* __restrict__ b0,
                const float* __restrict__ W1, const float* __restrict__ b1,
                const float* __restrict__ W2, const float* __restrict__ b2,
                const float* __restrict__ cbias,
                float* __restrict__ out)
{
    __shared__ float cb[16 * NCLS];   // cat tables (used by fg==3 blocks)

    const int t    = threadIdx.x;
    const int lane = t & 63;
    const int wv   = __builtin_amdgcn_readfirstlane(t >> 6);
    const int fg   = blockIdx.x >> 9;          // 0..3 (slow); 0-2 numeric, 3 cat
    const int rg   = blockIdx.x & (NRG - 1);   // fastest -> same-rg blocks share XCD
    const long long row0 = (long long)rg * RPB;

    const float* __restrict__ rp = inp + (row0 + lane) * NCOLS;  // + q*4096
    float* __restrict__ op_base  = out + (row0 + lane) * NCOLS;

    if (fg < 3) {
        // ---- numeric: wave wv owns features fbase..fbase+3 for 256 rows ----
        const int fbase = fg * 16 + wv * 4;

        #pragma unroll 1
        for (int j = 0; j < 4; ++j) {
            const int f = fbase + j;                      // wave-uniform -> s_load
            const float* __restrict__ w0f = W0 + f * H0N;
            const float* __restrict__ b0f = b0 + f * H0N;
            const float* __restrict__ w1f = W1 + f * H0N * H1N;
            const float* __restrict__ b1f = b1 + f * H1N;
            const float* __restrict__ w2f = W2 + f * H1N;

            // 4 rows' inputs; all 4 waves hit the same 64B line per row (L1)
            const float xc0 = rp[0 * 4096 + f];
            const float xc1 = rp[1 * 4096 + f];
            const float xc2 = rp[2 * 4096 + f];
            const float xc3 = rp[3 * 4096 + f];

            float h10[H1N], h11[H1N], h12[H1N], h13[H1N];
            #pragma unroll
            for (int o = 0; o < H1N; ++o) {
                const float bv = b1f[o];
                h10[o] = bv; h11[o] = bv; h12[o] = bv; h13[o] = bv;
            }

            #pragma unroll 10
            for (int k = 0; k < H0N; ++k) {
                const float w0k = w0f[k], b0k = b0f[k];   // SGPR
                const float a0 = fmaxf(fmaf(xc0, w0k, b0k), 0.f);
                const float a1 = fmaxf(fmaf(xc1, w0k, b0k), 0.f);
                const float a2 = fmaxf(fmaf(xc2, w0k, b0k), 0.f);
                const float a3 = fmaxf(fmaf(xc3, w0k, b0k), 0.f);
                const float* __restrict__ wk = w1f + k * H1N;
                #pragma unroll
                for (int o = 0; o < H1N; ++o) {
                    const float w = wk[o];                // SGPR, reused 4x
                    h10[o] = fmaf(a0, w, h10[o]);
                    h11[o] = fmaf(a1, w, h11[o]);
                    h12[o] = fmaf(a2, w, h12[o]);
                    h13[o] = fmaf(a3, w, h13[o]);
                }
            }

            const float b2v = b2[f];
            float acc0 = b2v, acc1 = b2v, acc2 = b2v, acc3 = b2v;
            #pragma unroll
            for (int o = 0; o < H1N; ++o) {
                const float w = w2f[o];
                acc0 = fmaf(fmaxf(h10[o], 0.f), w, acc0);
                acc1 = fmaf(fmaxf(h11[o], 0.f), w, acc1);
                acc2 = fmaf(fmaxf(h12[o], 0.f), w, acc2);
                acc3 = fmaf(fmaxf(h13[o], 0.f), w, acc3);
            }

            float* op = op_base + f;
            op[0 * 4096] = acc0;
            op[1 * 4096] = acc1;
            op[2 * 4096] = acc2;
            op[3 * 4096] = acc3;
        }
    } else {
        // ---- categorical: wave wv owns cat features wv*4..wv*4+3, 256 rows ----
        for (int i = t; i < 16 * NCLS; i += BLOCK) cb[i] = cbias[i];
        __syncthreads();

        const int jbase = wv * 4;
        #pragma unroll
        for (int jj = 0; jj < 4; ++jj) {
            const int j = jbase + jj;        // cat feature 0..15, col 48+j
            const float* tab = cb + j * NCLS;
            #pragma unroll
            for (int q = 0; q < 4; ++q) {
                const int idx = (int)rp[q * 4096 + NNUM + j];
                op_base[q * 4096 + NNUM + j] = tab[idx];
            }
        }
    }
}

extern "C" void kernel_launch(void* const* d_in, const int* in_sizes, int n_in,
                              void* d_out, int out_size, void* d_ws, size_t ws_size,
                              hipStream_t stream) {
    const float* inp   = (const float*)d_in[0];
    const float* W0    = (const float*)d_in[1];
    const float* b0    = (const float*)d_in[2];
    const float* W1    = (const float*)d_in[3];
    const float* b1    = (const float*)d_in[4];
    const float* W2    = (const float*)d_in[5];
    const float* b2    = (const float*)d_in[6];
    const float* cbias = (const float*)d_in[7];
    float* out = (float*)d_out;

    dim3 grid(4 * NRG);   // fg-major, rg fastest: 2048 blocks
    dim3 block(BLOCK);
    gam_kernel<<<grid, block, 0, stream>>>(inp, W0, b0, W1, b1, W2, b2, cbias, out);
}

// Round 12
// 231.044 us; speedup vs baseline: 1.6186x; 1.3373x over previous
//
#include <hip/hip_runtime.h>

// pyGAMNet round 10 kernel (3rd submit; R10/R11 benches were broker timeouts).
// R4's DRAM-clean pattern (16-col windows, LDS-transpose epilogue, float4
// stores) + 4 rows/lane weight amortization (1:4 s_load:FMA).
// R9 lesson: scattered dword global stores cost 12x HBM write amplification.

constexpr int NCOLS = 64;
constexpr int NNUM  = 48;
constexpr int NCLS  = 32;
constexpr int H0N   = 40;
constexpr int H1N   = 20;

#define BLOCK 256
#define RPB   256    // rows per block; row = row0 + q*64 + lane, q=0..3
#define NRG   512    // row-groups = 131072 / 256
#define TP    20     // LDS tile pad stride (16 cols used; 16B-aligned rows)

__global__ __launch_bounds__(BLOCK, 4)
void gam_kernel(const float* __restrict__ inp,
                const float* __restrict__ W0, const float* __restrict__ b0,
                const float* __restrict__ W1, const float* __restrict__ b1,
                const float* __restrict__ W2, const float* __restrict__ b2,
                const float* __restrict__ cbias,
                float* __restrict__ out)
{
    __shared__ float tile[RPB * TP];   // 20 KB: 256 rows x 16 result cols
    __shared__ float cb[16 * NCLS];    // 2 KB cat tables (fg==3 blocks)

    const int t    = threadIdx.x;
    const int lane = t & 63;
    const int wv   = __builtin_amdgcn_readfirstlane(t >> 6);
    const int fg   = blockIdx.x >> 9;          // 0..3 slow; 0-2 numeric, 3 cat
    const int rg   = blockIdx.x & (NRG - 1);   // fastest -> fg-siblings same XCD
    const long long row0 = (long long)rg * RPB;
    const int fbase = fg * 16;

    const float* __restrict__ rp = inp + (row0 + lane) * NCOLS;  // + q*4096

    if (fg < 3) {
        // ---- numeric: wave wv owns features fbase+wv*4 .. +3, 256 rows ----
        const int fwb = fbase + wv * 4;

        // rotating x prefetch (named regs only)
        float xn0 = rp[0 * 4096 + fwb];
        float xn1 = rp[1 * 4096 + fwb];
        float xn2 = rp[2 * 4096 + fwb];
        float xn3 = rp[3 * 4096 + fwb];

        #pragma unroll 1
        for (int ff = 0; ff < 4; ++ff) {
            const int f = fwb + ff;                       // wave-uniform -> s_load
            const float* __restrict__ w0f = W0 + f * H0N;
            const float* __restrict__ b0f = b0 + f * H0N;
            const float* __restrict__ w1f = W1 + f * H0N * H1N;
            const float* __restrict__ b1f = b1 + f * H1N;
            const float* __restrict__ w2f = W2 + f * H1N;

            const float xc0 = xn0, xc1 = xn1, xc2 = xn2, xc3 = xn3;
            if (ff < 3) {                                 // prefetch next x's
                xn0 = rp[0 * 4096 + f + 1];
                xn1 = rp[1 * 4096 + f + 1];
                xn2 = rp[2 * 4096 + f + 1];
                xn3 = rp[3 * 4096 + f + 1];
            }

            float h10[H1N], h11[H1N], h12[H1N], h13[H1N]; // 80 VGPR
            #pragma unroll
            for (int o = 0; o < H1N; ++o) {
                const float bv = b1f[o];
                h10[o] = bv; h11[o] = bv; h12[o] = bv; h13[o] = bv;
            }

            #pragma unroll 10
            for (int k = 0; k < H0N; ++k) {
                const float w0k = w0f[k], b0k = b0f[k];   // SGPR
                const float a0 = fmaxf(fmaf(xc0, w0k, b0k), 0.f);
                const float a1 = fmaxf(fmaf(xc1, w0k, b0k), 0.f);
                const float a2 = fmaxf(fmaf(xc2, w0k, b0k), 0.f);
                const float a3 = fmaxf(fmaf(xc3, w0k, b0k), 0.f);
                const float* __restrict__ wk = w1f + k * H1N;
                #pragma unroll
                for (int o = 0; o < H1N; ++o) {
                    const float w = wk[o];                // SGPR, reused 4x
                    h10[o] = fmaf(a0, w, h10[o]);
                    h11[o] = fmaf(a1, w, h11[o]);
                    h12[o] = fmaf(a2, w, h12[o]);
                    h13[o] = fmaf(a3, w, h13[o]);
                }
            }

            const float b2v = b2[f];
            float acc0 = b2v, acc1 = b2v, acc2 = b2v, acc3 = b2v;
            #pragma unroll
            for (int o = 0; o < H1N; ++o) {
                const float w = w2f[o];
                acc0 = fmaf(fmaxf(h10[o], 0.f), w, acc0);
                acc1 = fmaf(fmaxf(h11[o], 0.f), w, acc1);
                acc2 = fmaf(fmaxf(h12[o], 0.f), w, acc2);
                acc3 = fmaf(fmaxf(h13[o], 0.f), w, acc3);
            }

            const int c = wv * 4 + ff;                    // tile col 0..15
            tile[(0 * 64 + lane) * TP + c] = acc0;
            tile[(1 * 64 + lane) * TP + c] = acc1;
            tile[(2 * 64 + lane) * TP + c] = acc2;
            tile[(3 * 64 + lane) * TP + c] = acc3;
        }
    } else {
        // ---- categorical: cols 48..63 ----
        for (int i = t; i < 16 * NCLS; i += BLOCK) cb[i] = cbias[i];
        __syncthreads();

        #pragma unroll
        for (int ff = 0; ff < 4; ++ff) {
            const int j = wv * 4 + ff;                    // cat feature 0..15
            #pragma unroll
            for (int q = 0; q < 4; ++q) {
                const int idx = (int)rp[q * 4096 + NNUM + j];
                tile[(q * 64 + lane) * TP + j] = cb[j * NCLS + idx];
            }
        }
    }

    __syncthreads();

    // ---- epilogue: coalesced float4 stores, 64B segment per row ----
    const int r0 = t >> 2, c4 = t & 3;
    #pragma unroll
    for (int q = 0; q < 4; ++q) {
        const int r = q * 64 + r0;
        const float* src = &tile[r * TP + c4 * 4];
        float4 v = make_float4(src[0], src[1], src[2], src[3]);
        *reinterpret_cast<float4*>(out + (row0 + r) * NCOLS + fbase + c4 * 4) = v;
    }
}

extern "C" void kernel_launch(void* const* d_in, const int* in_sizes, int n_in,
                              void* d_out, int out_size, void* d_ws, size_t ws_size,
                              hipStream_t stream) {
    const float* inp   = (const float*)d_in[0];
    const float* W0    = (const float*)d_in[1];
    const float* b0    = (const float*)d_in[2];
    const float* W1    = (const float*)d_in[3];
    const float* b1    = (const float*)d_in[4];
    const float* W2    = (const float*)d_in[5];
    const float* b2    = (const float*)d_in[6];
    const float* cbias = (const float*)d_in[7];
    float* out = (float*)d_out;

    dim3 grid(4 * NRG);   // fg-major, rg fastest: 2048 blocks
    dim3 block(BLOCK);
    gam_kernel<<<grid, block, 0, stream>>>(inp, W0, b0, W1, b1, W2, b2, cbias, out);
}